// Round 14
// baseline (205.780 us; speedup 1.0000x reference)
//
#include <hip/hip_runtime.h>
#include <hip/hip_bf16.h>

static constexpr int TOTAL = 349525;
static constexpr int OFFS[11] = {0,1,5,21,85,341,1365,5461,21845,87381,349525};
// conv frags: 8 levels (L=1..8) x 9m x 2ks x 4cb x 64 lanes x 8 bf16
static constexpr size_t CONV_USH = (size_t)8*9*2*4*64*8;    // 294912 ushorts
static constexpr size_t EMB_USH  = (size_t)10*2*4*64*8;     //  40960 ushorts
static constexpr size_t FRAG_USH = CONV_USH + EMB_USH;      // 335872
static constexpr size_t FRAG_BYTES = FRAG_USH*2*2;          // hi+lo = 1343488 B
static constexpr size_t HPRE_BYTES = (size_t)(87381-85)*64*4;

typedef __attribute__((ext_vector_type(8))) short short8;
typedef __attribute__((ext_vector_type(4))) float f32x4;

__device__ __forceinline__ unsigned deint(unsigned v){
  v &= 0x55555555u;
  v = (v | (v>>1)) & 0x33333333u;
  v = (v | (v>>2)) & 0x0F0F0F0Fu;
  v = (v | (v>>4)) & 0x00FF00FFu;
  v = (v | (v>>8)) & 0x0000FFFFu;
  return v;
}
__device__ __forceinline__ unsigned ileave(unsigned v){
  v &= 0xFFFFu;
  v = (v | (v<<8)) & 0x00FF00FFu;
  v = (v | (v<<4)) & 0x0F0F0F0Fu;
  v = (v | (v<<2)) & 0x33333333u;
  v = (v | (v<<1)) & 0x55555555u;
  return v;
}
__device__ __forceinline__ unsigned short f2bh(float x){
  unsigned u = __float_as_uint(x);
  return (unsigned short)((u + 0x7FFFu + ((u>>16)&1u)) >> 16);
}
__device__ __forceinline__ float bh2f(unsigned short h){
  return __uint_as_float(((unsigned)h) << 16);
}
__device__ __forceinline__ void split8(float4 a, float4 b, short8 &hi, short8 &lo){
  float v[8] = {a.x,a.y,a.z,a.w,b.x,b.y,b.z,b.w};
  unsigned short hv[8], lv[8];
  #pragma unroll
  for (int j=0;j<8;++j){ hv[j]=f2bh(v[j]); lv[j]=f2bh(v[j]-bh2f(hv[j])); }
  hi = short8{(short)hv[0],(short)hv[1],(short)hv[2],(short)hv[3],
              (short)hv[4],(short)hv[5],(short)hv[6],(short)hv[7]};
  lo = short8{(short)lv[0],(short)lv[1],(short)lv[2],(short)lv[3],
              (short)lv[4],(short)lv[5],(short)lv[6],(short)lv[7]};
}

// ---------- W prep: conv_W[L=1..8] + emb_W[d=0..9] -> fragment-ordered bf16 hi/lo ----------
__global__ __launch_bounds__(256) void k_wprep(const float* __restrict__ convW,
    const float* __restrict__ embW,
    unsigned short* __restrict__ WH, unsigned short* __restrict__ WLo){
  int tid = blockIdx.x*256 + threadIdx.x;
  if (tid >= 41984) return;
  const float* src;
  size_t dst;
  if (tid < 36864){                       // conv region
    int l=tid&63, cb=(tid>>6)&3, ks=(tid>>8)&1;
    int x=tid>>9; int m=x%9, Lp=x/9;      // L = Lp+1
    int k0=ks*32+((l>>4)<<3), ch=cb*16+(l&15);
    src = convW + (size_t)(Lp+1)*36864 + (size_t)(m*64+k0)*64 + ch;
    dst = (size_t)tid*8;
  } else {                                // emb region
    int t2 = tid - 36864;
    int l=t2&63, cb=(t2>>6)&3, ks=(t2>>8)&1, d=t2>>9;
    int k0=ks*32+((l>>4)<<3), ch=cb*16+(l&15);
    src = embW + (size_t)d*4096 + (size_t)k0*64 + ch;
    dst = CONV_USH + (size_t)t2*8;
  }
  unsigned short hv[8], lv[8];
  #pragma unroll
  for (int j=0;j<8;++j){
    float v = src[(size_t)j*64];
    unsigned short h = f2bh(v);
    hv[j] = h;
    lv[j] = f2bh(v - bh2f(h));
  }
  short8 vh = {(short)hv[0],(short)hv[1],(short)hv[2],(short)hv[3],
               (short)hv[4],(short)hv[5],(short)hv[6],(short)hv[7]};
  short8 vl = {(short)lv[0],(short)lv[1],(short)lv[2],(short)lv[3],
               (short)lv[4],(short)lv[5],(short)lv[6],(short)lv[7]};
  *(short8*)(WH  + dst) = vh;
  *(short8*)(WLo + dst) = vl;
}

// ---------- in_proj (round-7 form + hpre mirror) ----------
__global__ __launch_bounds__(256) void k_inproj(const float* __restrict__ feat,
    const float* __restrict__ W, const float* __restrict__ B,
    float* __restrict__ h, float* __restrict__ hpre){
  __shared__ float Alt[128][44];
  __shared__ float Wl[40][68];
  int t = threadIdx.x;
  int base = blockIdx.x * 128;
  for (int idx = t; idx < 40*64; idx += 256)
    Wl[idx >> 6][idx & 63] = W[idx];
  if (t < 128){
    int g = base + t;
    float* row = Alt[t];
    if (g < TOTAL){
      int d = 0;
      #pragma unroll
      for (int i = 1; i <= 9; ++i) if (g >= OFFS[i]) d = i;
      int local = g - OFFS[d];
      unsigned ix = deint((unsigned)local), iy = deint(((unsigned)local) >> 1);
      float inv = 1.0f / (float)(1 << d);
      float px = ((float)ix + 0.5f) * inv;
      float py = ((float)iy + 0.5f) * inv;
      float pd = (float)d * (1.0f/9.0f);
      row[0] = feat[g]; row[1] = px; row[2] = py; row[3] = pd;
      float p3[3] = {px, py, pd};
      #pragma unroll
      for (int c = 0; c < 3; ++c){
        float s, co;
        __sincosf(6.28318530717958647692f * p3[c], &s, &co);
        float* rb = row + 4 + c*12;
        #pragma unroll
        for (int f = 0; f < 6; ++f){
          rb[f] = s; rb[6+f] = co;
          float s2 = 2.f*s*co, c2 = 1.f - 2.f*s*s;
          s = s2; co = c2;
        }
      }
    } else {
      #pragma unroll
      for (int k = 0; k < 40; ++k) row[k] = 0.f;
    }
  }
  __syncthreads();
  int tr = t >> 3, tc = t & 7;
  float acc[4][8];
  #pragma unroll
  for (int i=0;i<4;++i)
    #pragma unroll
    for (int c=0;c<8;++c) acc[i][c] = 0.f;
  #pragma unroll 2
  for (int k4 = 0; k4 < 10; ++k4){
    float av4[4][4];
    #pragma unroll
    for (int i=0;i<4;++i){
      float4 aa = *(const float4*)&Alt[tr*4+i][k4*4];
      av4[i][0]=aa.x; av4[i][1]=aa.y; av4[i][2]=aa.z; av4[i][3]=aa.w;
    }
    #pragma unroll
    for (int j=0;j<4;++j){
      float4 lo = *(const float4*)&Wl[k4*4+j][tc*8];
      float4 hi = *(const float4*)&Wl[k4*4+j][tc*8+4];
      float wv[8];
      wv[0]=lo.x; wv[1]=lo.y; wv[2]=lo.z; wv[3]=lo.w;
      wv[4]=hi.x; wv[5]=hi.y; wv[6]=hi.z; wv[7]=hi.w;
      #pragma unroll
      for (int i=0;i<4;++i){
        float a = av4[i][j];
        #pragma unroll
        for (int c=0;c<8;++c) acc[i][c] += a*wv[c];
      }
    }
  }
  #pragma unroll
  for (int i=0;i<4;++i){
    int g = base + tr*4 + i;
    if (g >= TOTAL) continue;
    float ov[8];
    #pragma unroll
    for (int c=0;c<8;++c) ov[c] = acc[i][c] + B[tc*8+c];
    float* dst = &h[(size_t)g*64 + tc*8];
    *(float4*)dst       = *(const float4*)&ov[0];
    *(float4*)(dst + 4) = *(const float4*)&ov[4];
    if (hpre && g >= OFFS[4] && g < OFFS[9]){
      float* dp = hpre + (size_t)(g - OFFS[4])*64 + tc*8;
      *(float4*)dp       = *(const float4*)&ov[0];
      *(float4*)(dp + 4) = *(const float4*)&ov[4];
    }
  }
}

// ---------- conv (halo + fused pool + MFMA bf16-split) — verified ----------
__global__ __launch_bounds__(256) void k_conv(float* __restrict__ h,
    const float* __restrict__ hPar,
    const unsigned short* __restrict__ WHl, const unsigned short* __restrict__ WLl,
    const float* __restrict__ Bb, int N, int offL, int offC, int lbits){
  __shared__ unsigned short haloH[100*72];
  __shared__ unsigned short haloL[100*72];
  __shared__ int hkey[100];
  int t = threadIdx.x;
  int nb = blockIdx.x * 64;
  int res = 1 << lbits;
  if (t < 100){
    int i = t % 10, j = t / 10;
    int gx = (int)deint((unsigned)nb) - 1 + i;
    int gy = (int)deint(((unsigned)nb)>>1) - 1 + j;
    bool ok = (gx>=0 && gy>=0 && gx<res && gy<res);
    hkey[t] = ok ? (int)(ileave((unsigned)gx) | (ileave((unsigned)gy)<<1)) : -1;
  }
  __syncthreads();
  const float* hC = h + (size_t)offC*64;
  for (int e = t; e < 1600; e += 256){
    int hi_ = e >> 4, u = e & 15;
    int key = hkey[hi_];
    float4 r = make_float4(0.f,0.f,0.f,0.f);
    if (key >= 0){
      const float4* c = (const float4*)(hC + (size_t)(4*key)*64) + u;
      float4 c0 = c[0], c1 = c[16], c2 = c[32], c3 = c[48];
      float4 pr = *((const float4*)(hPar + (size_t)key*64) + u);
      r.x = 0.25f*(c0.x+c1.x+c2.x+c3.x) + pr.x;
      r.y = 0.25f*(c0.y+c1.y+c2.y+c3.y) + pr.y;
      r.z = 0.25f*(c0.z+c1.z+c2.z+c3.z) + pr.z;
      r.w = 0.25f*(c0.w+c1.w+c2.w+c3.w) + pr.w;
    }
    unsigned short h0=f2bh(r.x), h1=f2bh(r.y), h2=f2bh(r.z), h3=f2bh(r.w);
    ushort4 rh = make_ushort4(h0,h1,h2,h3);
    ushort4 rl = make_ushort4(f2bh(r.x - bh2f(h0)), f2bh(r.y - bh2f(h1)),
                              f2bh(r.z - bh2f(h2)), f2bh(r.w - bh2f(h3)));
    *(ushort4*)&haloH[hi_*72 + u*4] = rh;
    *(ushort4*)&haloL[hi_*72 + u*4] = rl;
  }
  __syncthreads();

  int cb   = __builtin_amdgcn_readfirstlane((int)(threadIdx.x >> 6));
  int lane = t & 63;
  int q = lane >> 4;
  int chl = cb*16 + (lane & 15);
  int lx0,ly0,lx1,ly1,lx2,ly2,lx3,ly3;
  {
    int n0 = (lane&15), n1 = 16+(lane&15), n2 = 32+(lane&15), n3 = 48+(lane&15);
    lx0=(int)deint((unsigned)n0); ly0=(int)deint(((unsigned)n0)>>1);
    lx1=(int)deint((unsigned)n1); ly1=(int)deint(((unsigned)n1)>>1);
    lx2=(int)deint((unsigned)n2); ly2=(int)deint(((unsigned)n2)>>1);
    lx3=(int)deint((unsigned)n3); ly3=(int)deint(((unsigned)n3)>>1);
  }
  f32x4 acc0 = {0.f,0.f,0.f,0.f}, acc1 = acc0, acc2 = acc0, acc3 = acc0;

  #pragma unroll 1
  for (int dy=0;dy<3;++dy){
    #pragma unroll 1
    for (int dx=0;dx<3;++dx){
      int m = dy*3 + dx;
      int r0 = (ly0+dy)*10 + lx0+dx;
      int r1 = (ly1+dy)*10 + lx1+dx;
      int r2 = (ly2+dy)*10 + lx2+dx;
      int r3 = (ly3+dy)*10 + lx3+dx;
      #pragma unroll
      for (int ks=0;ks<2;++ks){
        const unsigned short* fp = WHl + ((size_t)((m*2+ks)*4 + cb)*64 + lane)*8;
        const unsigned short* fq = WLl + ((size_t)((m*2+ks)*4 + cb)*64 + lane)*8;
        short8 bh = *(const short8*)fp;
        short8 bl = *(const short8*)fq;
        int so = (ks*4 + q)*8;
        short8 ah0 = *(const short8*)&haloH[r0*72 + so];
        short8 al0 = *(const short8*)&haloL[r0*72 + so];
        short8 ah1 = *(const short8*)&haloH[r1*72 + so];
        short8 al1 = *(const short8*)&haloL[r1*72 + so];
        short8 ah2 = *(const short8*)&haloH[r2*72 + so];
        short8 al2 = *(const short8*)&haloL[r2*72 + so];
        short8 ah3 = *(const short8*)&haloH[r3*72 + so];
        short8 al3 = *(const short8*)&haloL[r3*72 + so];
        acc0 = __builtin_amdgcn_mfma_f32_16x16x32_bf16(ah0, bh, acc0, 0,0,0);
        acc1 = __builtin_amdgcn_mfma_f32_16x16x32_bf16(ah1, bh, acc1, 0,0,0);
        acc2 = __builtin_amdgcn_mfma_f32_16x16x32_bf16(ah2, bh, acc2, 0,0,0);
        acc3 = __builtin_amdgcn_mfma_f32_16x16x32_bf16(ah3, bh, acc3, 0,0,0);
        acc0 = __builtin_amdgcn_mfma_f32_16x16x32_bf16(al0, bh, acc0, 0,0,0);
        acc1 = __builtin_amdgcn_mfma_f32_16x16x32_bf16(al1, bh, acc1, 0,0,0);
        acc2 = __builtin_amdgcn_mfma_f32_16x16x32_bf16(al2, bh, acc2, 0,0,0);
        acc3 = __builtin_amdgcn_mfma_f32_16x16x32_bf16(al3, bh, acc3, 0,0,0);
        acc0 = __builtin_amdgcn_mfma_f32_16x16x32_bf16(ah0, bl, acc0, 0,0,0);
        acc1 = __builtin_amdgcn_mfma_f32_16x16x32_bf16(ah1, bl, acc1, 0,0,0);
        acc2 = __builtin_amdgcn_mfma_f32_16x16x32_bf16(ah2, bl, acc2, 0,0,0);
        acc3 = __builtin_amdgcn_mfma_f32_16x16x32_bf16(ah3, bl, acc3, 0,0,0);
      }
    }
  }
  float bias = Bb[chl];
  int rowb = q*4;
  float* hO = h + (size_t)(offL + nb)*64;
  #pragma unroll
  for (int reg=0;reg<4;++reg){
    int n0 = rowb + reg;
    float v0 = acc0[reg] + bias; if (nb + n0      < N) hO[(size_t)(n0     )*64 + chl] = v0 > 0.f ? v0 : 0.f;
    float v1 = acc1[reg] + bias; if (nb + n0 + 16 < N) hO[(size_t)(n0 + 16)*64 + chl] = v1 > 0.f ? v1 : 0.f;
    float v2 = acc2[reg] + bias; if (nb + n0 + 32 < N) hO[(size_t)(n0 + 32)*64 + chl] = v2 > 0.f ? v2 : 0.f;
    float v3 = acc3[reg] + bias; if (nb + n0 + 48 < N) hO[(size_t)(n0 + 48)*64 + chl] = v3 > 0.f ? v3 : 0.f;
  }
}

// ---------- emb tile: one wave embeds 16 nodes of level d at rowbase ----------
__device__ __forceinline__ void emb_tile(float* __restrict__ h,
    const unsigned short* __restrict__ EH, const unsigned short* __restrict__ ELo,
    const float* __restrict__ embB, const float* __restrict__ lng,
    const float* __restrict__ lnb, const float* __restrict__ gain,
    int d, size_t rowbase, int validN, int lane){
  int q = lane >> 4, li = lane & 15;
  const float* rp = h + (rowbase + li)*64 + q*8;
  float4 a0 = *(const float4*)rp;
  float4 a1 = *(const float4*)(rp + 4);
  float4 a2 = *(const float4*)(rp + 32);
  float4 a3 = *(const float4*)(rp + 36);
  short8 ah0, al0, ah1, al1;
  split8(a0, a1, ah0, al0);
  split8(a2, a3, ah1, al1);
  f32x4 acc0 = {0.f,0.f,0.f,0.f}, acc1 = acc0, acc2 = acc0, acc3 = acc0;
  #define EMB_CB(CB, ACC) { \
    size_t f0 = (((size_t)(d*2+0)*4 + (CB))*64 + lane)*8; \
    size_t f1 = (((size_t)(d*2+1)*4 + (CB))*64 + lane)*8; \
    short8 bh0 = *(const short8*)(EH + f0); \
    short8 bl0 = *(const short8*)(ELo + f0); \
    short8 bh1 = *(const short8*)(EH + f1); \
    short8 bl1 = *(const short8*)(ELo + f1); \
    ACC = __builtin_amdgcn_mfma_f32_16x16x32_bf16(ah0, bh0, ACC, 0,0,0); \
    ACC = __builtin_amdgcn_mfma_f32_16x16x32_bf16(al0, bh0, ACC, 0,0,0); \
    ACC = __builtin_amdgcn_mfma_f32_16x16x32_bf16(ah0, bl0, ACC, 0,0,0); \
    ACC = __builtin_amdgcn_mfma_f32_16x16x32_bf16(ah1, bh1, ACC, 0,0,0); \
    ACC = __builtin_amdgcn_mfma_f32_16x16x32_bf16(al1, bh1, ACC, 0,0,0); \
    ACC = __builtin_amdgcn_mfma_f32_16x16x32_bf16(ah1, bl1, ACC, 0,0,0); }
  EMB_CB(0, acc0)
  EMB_CB(1, acc1)
  EMB_CB(2, acc2)
  EMB_CB(3, acc3)
  #undef EMB_CB
  float b0 = embB[d*64 +      li];
  float b1 = embB[d*64 + 16 + li];
  float b2 = embB[d*64 + 32 + li];
  float b3 = embB[d*64 + 48 + li];
  float mu[4], rs[4];
  float z0[4], z1[4], z2[4], z3[4];
  #pragma unroll
  for (int r=0;r<4;++r){
    z0[r] = acc0[r] + b0;
    z1[r] = acc1[r] + b1;
    z2[r] = acc2[r] + b2;
    z3[r] = acc3[r] + b3;
    float s  = z0[r] + z1[r] + z2[r] + z3[r];
    float qv = z0[r]*z0[r] + z1[r]*z1[r] + z2[r]*z2[r] + z3[r]*z3[r];
    #pragma unroll
    for (int mk=1; mk<16; mk<<=1){
      s  += __shfl_xor(s, mk, 64);
      qv += __shfl_xor(qv, mk, 64);
    }
    float m = s * 0.015625f;
    mu[r] = m;
    rs[r] = rsqrtf(qv * 0.015625f - m*m + 1e-5f);
  }
  float g0 = lng[d*64 +      li], l0 = lnb[d*64 +      li];
  float g1 = lng[d*64 + 16 + li], l1 = lnb[d*64 + 16 + li];
  float g2 = lng[d*64 + 32 + li], l2 = lnb[d*64 + 32 + li];
  float g3 = lng[d*64 + 48 + li], l3 = lnb[d*64 + 48 + li];
  float gn = gain[d];
  #pragma unroll
  for (int r=0;r<4;++r){
    int ni = q*4 + r;
    if (ni < validN){
      float* row = h + (rowbase + ni)*64;
      row[     li] = ((z0[r] - mu[r])*rs[r]*g0 + l0)*gn;
      row[16 + li] = ((z1[r] - mu[r])*rs[r]*g1 + l1)*gn;
      row[32 + li] = ((z2[r] - mu[r])*rs[r]*g2 + l2)*gn;
      row[48 + li] = ((z3[r] - mu[r])*rs[r]*g3 + l3)*gn;
    }
  }
}

// ---------- tail level (on-chip): m-loop reads Pt; pool next Pt from REGISTERS ----------
template<int L>
__device__ __forceinline__ void tail_level2(float* __restrict__ h,
    const unsigned short* __restrict__ WHc, const unsigned short* __restrict__ WLc,
    const float* __restrict__ convB, const float* __restrict__ Hpar,
    unsigned short* __restrict__ PtH, unsigned short* __restrict__ PtL, int t){
  constexpr int Np  = 1 << (2*L);
  constexpr int NTt = (Np + 15)/16;
  constexpr int TG  = (NTt + 3)/4;
  constexpr int res = 1 << L;
  int w  = t >> 6;
  int cb = __builtin_amdgcn_readfirstlane(w & 3);
  int tg = __builtin_amdgcn_readfirstlane(w >> 2);
  int lane = t & 63;
  int q = lane >> 4, li = lane & 15;
  int chl = cb*16 + li;
  int lx[TG], ly[TG];
  #pragma unroll
  for (int i=0;i<TG;++i){
    unsigned n = (unsigned)((tg*TG + i)*16 + li);
    lx[i] = (int)deint(n); ly[i] = (int)deint(n >> 1);
  }
  f32x4 acc[TG];
  #pragma unroll
  for (int i=0;i<TG;++i) acc[i] = f32x4{0.f,0.f,0.f,0.f};
  short8 bh0, bl0, bh1, bl1;
  {
    size_t f0 = ((size_t)(0*4 + cb)*64 + lane)*8;
    size_t f1 = ((size_t)(1*4 + cb)*64 + lane)*8;
    bh0 = *(const short8*)(WHc + f0); bl0 = *(const short8*)(WLc + f0);
    bh1 = *(const short8*)(WHc + f1); bl1 = *(const short8*)(WLc + f1);
  }
  #pragma unroll 1
  for (int m=0;m<9;++m){
    short8 nh0, nl0, nh1, nl1;
    if (m < 8){
      size_t f0 = ((size_t)(((m+1)*2+0)*4 + cb)*64 + lane)*8;
      size_t f1 = ((size_t)(((m+1)*2+1)*4 + cb)*64 + lane)*8;
      nh0 = *(const short8*)(WHc + f0); nl0 = *(const short8*)(WLc + f0);
      nh1 = *(const short8*)(WHc + f1); nl1 = *(const short8*)(WLc + f1);
    }
    int dy = m/3 - 1, dx = m%3 - 1;
    #pragma unroll
    for (int i=0;i<TG;++i){
      int nx = lx[i]+dx, ny = ly[i]+dy;
      int key = (nx>=0 && ny>=0 && nx<res && ny<res)
              ? (int)(ileave((unsigned)nx) | (ileave((unsigned)ny)<<1)) : Np;
      const unsigned short* pH = PtH + key*72;
      const unsigned short* pL = PtL + key*72;
      short8 ah0 = *(const short8*)(pH + q*8);
      short8 al0 = *(const short8*)(pL + q*8);
      short8 ah1 = *(const short8*)(pH + 32 + q*8);
      short8 al1 = *(const short8*)(pL + 32 + q*8);
      acc[i] = __builtin_amdgcn_mfma_f32_16x16x32_bf16(ah0, bh0, acc[i], 0,0,0);
      acc[i] = __builtin_amdgcn_mfma_f32_16x16x32_bf16(al0, bh0, acc[i], 0,0,0);
      acc[i] = __builtin_amdgcn_mfma_f32_16x16x32_bf16(ah0, bl0, acc[i], 0,0,0);
      acc[i] = __builtin_amdgcn_mfma_f32_16x16x32_bf16(ah1, bh1, acc[i], 0,0,0);
      acc[i] = __builtin_amdgcn_mfma_f32_16x16x32_bf16(al1, bh1, acc[i], 0,0,0);
      acc[i] = __builtin_amdgcn_mfma_f32_16x16x32_bf16(ah1, bl1, acc[i], 0,0,0);
    }
    if (m < 8){ bh0 = nh0; bl0 = nl0; bh1 = nh1; bl1 = nl1; }
  }
  float bias = convB[L*64 + chl];
  float vq[TG][4];
  #pragma unroll
  for (int i=0;i<TG;++i){
    #pragma unroll
    for (int reg=0;reg<4;++reg){
      int ni = (tg*TG + i)*16 + q*4 + reg;
      float v = acc[i][reg] + bias;
      v = v > 0.f ? v : 0.f;
      vq[i][reg] = v;
      if (ni < Np) h[(size_t)(OFFS[L] + ni)*64 + chl] = v;
    }
  }
  __syncthreads();   // all waves done READING Pt(L) before overwriting with Pt(L-1)
  if (L > 1){
    constexpr int Pp = Np/4;
    #pragma unroll
    for (int i=0;i<TG;++i){
      int p = (tg*TG + i)*4 + q;
      if (p < Pp){
        float pooled = 0.25f*(vq[i][0]+vq[i][1]+vq[i][2]+vq[i][3])
                     + Hpar[(size_t)(OFFS[L-1] + p)*64 + chl];
        unsigned short hh = f2bh(pooled);
        PtH[p*72 + chl] = hh;
        PtL[p*72 + chl] = f2bh(pooled - bh2f(hh));
      }
    }
    if (t < 64){ PtH[Pp*72 + t] = 0; PtL[Pp*72 + t] = 0; }
  } else {
    if (tg == 0 && q == 0){
      float pooled = 0.25f*(vq[0][0]+vq[0][1]+vq[0][2]+vq[0][3]) + Hpar[chl];
      h[chl] = pooled;
    }
  }
  __syncthreads();
}

// ---------- fused: block 0 = tail (levels 4..1 + emb 0..5); blocks 1.. = emb levels 6..9 ----------
__global__ __launch_bounds__(1024) void k_tail_emb(float* __restrict__ h,
    const unsigned short* __restrict__ WH, const unsigned short* __restrict__ WLo,
    const float* __restrict__ convB,
    const unsigned short* __restrict__ EH, const unsigned short* __restrict__ ELo,
    const float* __restrict__ embB, const float* __restrict__ lng,
    const float* __restrict__ lnb, const float* __restrict__ gain){
  __shared__ unsigned short PtH[257*72];
  __shared__ unsigned short PtL[257*72];
  __shared__ float Hpar[85*64];
  int t = threadIdx.x;
  if (blockIdx.x != 0){
    // emb for levels 6..9 in 512-node chunks (never straddles a level)
    int bb = blockIdx.x - 1;
    int d, start;
    if      (bb < 8)  { d=6; start=0;   }
    else if (bb < 40) { d=7; start=8;   }
    else if (bb < 168){ d=8; start=40;  }
    else              { d=9; start=168; }
    size_t base = (size_t)OFFS[d] + (size_t)(bb - start)*512;
    int w = t >> 6, lane = t & 63;
    emb_tile(h, EH, ELo, embB, lng, lnb, gain, d, base + (size_t)w*16,      16, lane);
    emb_tile(h, EH, ELo, embB, lng, lnb, gain, d, base + (size_t)(w+16)*16, 16, lane);
    return;
  }
  // ---- block 0: tail ----
  for (int e = t; e < 85*16; e += 1024)
    ((float4*)Hpar)[e] = ((const float4*)h)[e];
  // stage Pt for L=4: pooled = 0.25*sum(children h[5]) + parent h[4]; row 256 = zero
  for (int e = t; e < 257*16; e += 1024){
    int node = e >> 4, u = e & 15;
    float4 r = make_float4(0.f,0.f,0.f,0.f);
    if (node < 256){
      const float4* c = (const float4*)(h + (size_t)(OFFS[5] + 4*node)*64) + u;
      float4 c0 = c[0], c1 = c[16], c2 = c[32], c3 = c[48];
      float4 pr = *((const float4*)(h + (size_t)(OFFS[4] + node)*64) + u);
      r.x = 0.25f*(c0.x+c1.x+c2.x+c3.x) + pr.x;
      r.y = 0.25f*(c0.y+c1.y+c2.y+c3.y) + pr.y;
      r.z = 0.25f*(c0.z+c1.z+c2.z+c3.z) + pr.z;
      r.w = 0.25f*(c0.w+c1.w+c2.w+c3.w) + pr.w;
    }
    unsigned short h0=f2bh(r.x), h1=f2bh(r.y), h2=f2bh(r.z), h3=f2bh(r.w);
    *(ushort4*)&PtH[node*72 + u*4] = make_ushort4(h0,h1,h2,h3);
    *(ushort4*)&PtL[node*72 + u*4] = make_ushort4(
        f2bh(r.x - bh2f(h0)), f2bh(r.y - bh2f(h1)),
        f2bh(r.z - bh2f(h2)), f2bh(r.w - bh2f(h3)));
  }
  __syncthreads();
  tail_level2<4>(h, WH + (size_t)3*36864, WLo + (size_t)3*36864, convB, Hpar, PtH, PtL, t);
  tail_level2<3>(h, WH + (size_t)2*36864, WLo + (size_t)2*36864, convB, Hpar, PtH, PtL, t);
  tail_level2<2>(h, WH + (size_t)1*36864, WLo + (size_t)1*36864, convB, Hpar, PtH, PtL, t);
  tail_level2<1>(h, WH,                   WLo,                   convB, Hpar, PtH, PtL, t);
  // epilogue: emb for levels 0..5 (h rows 0..1365, all final; 87 tile-jobs over 16 waves)
  int w = t >> 6, lane = t & 63;
  for (int j = w; j < 87; j += 16){
    int d, tile;
    if (j < 64)      { d=5; tile=j;    }
    else if (j < 80) { d=4; tile=j-64; }
    else if (j < 84) { d=3; tile=j-80; }
    else if (j == 84){ d=2; tile=0;    }
    else if (j == 85){ d=1; tile=0;    }
    else             { d=0; tile=0;    }
    int Nlev = 1 << (2*d);
    emb_tile(h, EH, ELo, embB, lng, lnb, gain, d,
             (size_t)OFFS[d] + (size_t)tile*16, Nlev - tile*16, lane);
  }
}

extern "C" void kernel_launch(void* const* d_in, const int* in_sizes, int n_in,
                              void* d_out, int out_size, void* d_ws, size_t ws_size,
                              hipStream_t stream) {
  (void)in_sizes; (void)n_in; (void)out_size;
  const float* feat  = (const float*)d_in[0];
  const float* ipW   = (const float*)d_in[1];
  const float* ipB   = (const float*)d_in[2];
  const float* convW = (const float*)d_in[3];
  const float* convB = (const float*)d_in[4];
  const float* embW  = (const float*)d_in[5];
  const float* embB  = (const float*)d_in[6];
  const float* lng   = (const float*)d_in[7];
  const float* lnb   = (const float*)d_in[8];
  const float* gain  = (const float*)d_in[9];
  float* h = (float*)d_out;

  unsigned short* WH  = (unsigned short*)d_ws;
  unsigned short* WLo = WH + FRAG_USH;
  float* hpre = (ws_size >= FRAG_BYTES + HPRE_BYTES)
              ? (float*)((char*)d_ws + FRAG_BYTES) : nullptr;

  k_wprep<<<164, 256, 0, stream>>>(convW, embW, WH, WLo);
  k_inproj<<<(TOTAL + 127)/128, 256, 0, stream>>>(feat, ipW, ipB, h, hpre);

  // levels L=8..5 on the grid; L=4..1 + all emb inside the fused kernel
  for (int L = 8; L >= 5; --L){
    int Np = 1 << (2*L);
    const float* hPar = hpre ? (hpre + (size_t)(OFFS[L] - OFFS[4])*64)
                             : (h + (size_t)OFFS[L]*64);
    k_conv<<<Np/64, 256, 0, stream>>>(h, hPar,
        WH  + (size_t)(L-1)*36864, WLo + (size_t)(L-1)*36864,
        convB + (size_t)L*64, Np, OFFS[L], OFFS[L+1], L);
  }

  // fused: 1 tail block + 680 emb blocks (levels 6..9), concurrent
  k_tail_emb<<<681, 1024, 0, stream>>>(h, WH, WLo, convB,
      WH + CONV_USH, WLo + CONV_USH, embB, lng, lnb, gain);
}

// Round 15
// 199.972 us; speedup vs baseline: 1.0290x; 1.0290x over previous
//
#include <hip/hip_runtime.h>
#include <hip/hip_bf16.h>

static constexpr int TOTAL = 349525;
static constexpr int OFFS[11] = {0,1,5,21,85,341,1365,5461,21845,87381,349525};
// conv frags: 8 levels (L=1..8) x 9m x 2ks x 4cb x 64 lanes x 8 bf16
static constexpr size_t CONV_USH = (size_t)8*9*2*4*64*8;    // 294912 ushorts
static constexpr size_t EMB_USH  = (size_t)10*2*4*64*8;     //  40960 ushorts
static constexpr size_t FRAG_USH = CONV_USH + EMB_USH;      // 335872
static constexpr size_t FRAG_BYTES = FRAG_USH*2*2;          // hi+lo = 1343488 B
static constexpr size_t HPRE_BYTES = (size_t)(87381-85)*64*4;

typedef __attribute__((ext_vector_type(8))) short short8;
typedef __attribute__((ext_vector_type(4))) float f32x4;

__device__ __forceinline__ unsigned deint(unsigned v){
  v &= 0x55555555u;
  v = (v | (v>>1)) & 0x33333333u;
  v = (v | (v>>2)) & 0x0F0F0F0Fu;
  v = (v | (v>>4)) & 0x00FF00FFu;
  v = (v | (v>>8)) & 0x0000FFFFu;
  return v;
}
__device__ __forceinline__ unsigned ileave(unsigned v){
  v &= 0xFFFFu;
  v = (v | (v<<8)) & 0x00FF00FFu;
  v = (v | (v<<4)) & 0x0F0F0F0Fu;
  v = (v | (v<<2)) & 0x33333333u;
  v = (v | (v<<1)) & 0x55555555u;
  return v;
}
__device__ __forceinline__ unsigned short f2bh(float x){
  unsigned u = __float_as_uint(x);
  return (unsigned short)((u + 0x7FFFu + ((u>>16)&1u)) >> 16);
}
__device__ __forceinline__ float bh2f(unsigned short h){
  return __uint_as_float(((unsigned)h) << 16);
}
__device__ __forceinline__ void split8(float4 a, float4 b, short8 &hi, short8 &lo){
  float v[8] = {a.x,a.y,a.z,a.w,b.x,b.y,b.z,b.w};
  unsigned short hv[8], lv[8];
  #pragma unroll
  for (int j=0;j<8;++j){ hv[j]=f2bh(v[j]); lv[j]=f2bh(v[j]-bh2f(hv[j])); }
  hi = short8{(short)hv[0],(short)hv[1],(short)hv[2],(short)hv[3],
              (short)hv[4],(short)hv[5],(short)hv[6],(short)hv[7]};
  lo = short8{(short)lv[0],(short)lv[1],(short)lv[2],(short)lv[3],
              (short)lv[4],(short)lv[5],(short)lv[6],(short)lv[7]};
}

// ---------- W prep: conv_W[L=1..8] + emb_W[d=0..9] -> fragment-ordered bf16 hi/lo ----------
__global__ __launch_bounds__(256) void k_wprep(const float* __restrict__ convW,
    const float* __restrict__ embW,
    unsigned short* __restrict__ WH, unsigned short* __restrict__ WLo){
  int tid = blockIdx.x*256 + threadIdx.x;
  if (tid >= 41984) return;
  const float* src;
  size_t dst;
  if (tid < 36864){                       // conv region
    int l=tid&63, cb=(tid>>6)&3, ks=(tid>>8)&1;
    int x=tid>>9; int m=x%9, Lp=x/9;      // L = Lp+1
    int k0=ks*32+((l>>4)<<3), ch=cb*16+(l&15);
    src = convW + (size_t)(Lp+1)*36864 + (size_t)(m*64+k0)*64 + ch;
    dst = (size_t)tid*8;
  } else {                                // emb region
    int t2 = tid - 36864;
    int l=t2&63, cb=(t2>>6)&3, ks=(t2>>8)&1, d=t2>>9;
    int k0=ks*32+((l>>4)<<3), ch=cb*16+(l&15);
    src = embW + (size_t)d*4096 + (size_t)k0*64 + ch;
    dst = CONV_USH + (size_t)t2*8;
  }
  unsigned short hv[8], lv[8];
  #pragma unroll
  for (int j=0;j<8;++j){
    float v = src[(size_t)j*64];
    unsigned short h = f2bh(v);
    hv[j] = h;
    lv[j] = f2bh(v - bh2f(h));
  }
  short8 vh = {(short)hv[0],(short)hv[1],(short)hv[2],(short)hv[3],
               (short)hv[4],(short)hv[5],(short)hv[6],(short)hv[7]};
  short8 vl = {(short)lv[0],(short)lv[1],(short)lv[2],(short)lv[3],
               (short)lv[4],(short)lv[5],(short)lv[6],(short)lv[7]};
  *(short8*)(WH  + dst) = vh;
  *(short8*)(WLo + dst) = vl;
}

// ---------- in_proj (verified form + hpre mirror) ----------
__global__ __launch_bounds__(256) void k_inproj(const float* __restrict__ feat,
    const float* __restrict__ W, const float* __restrict__ B,
    float* __restrict__ h, float* __restrict__ hpre){
  __shared__ float Alt[128][44];
  __shared__ float Wl[40][68];
  int t = threadIdx.x;
  int base = blockIdx.x * 128;
  for (int idx = t; idx < 40*64; idx += 256)
    Wl[idx >> 6][idx & 63] = W[idx];
  if (t < 128){
    int g = base + t;
    float* row = Alt[t];
    if (g < TOTAL){
      int d = 0;
      #pragma unroll
      for (int i = 1; i <= 9; ++i) if (g >= OFFS[i]) d = i;
      int local = g - OFFS[d];
      unsigned ix = deint((unsigned)local), iy = deint(((unsigned)local) >> 1);
      float inv = 1.0f / (float)(1 << d);
      float px = ((float)ix + 0.5f) * inv;
      float py = ((float)iy + 0.5f) * inv;
      float pd = (float)d * (1.0f/9.0f);
      row[0] = feat[g]; row[1] = px; row[2] = py; row[3] = pd;
      float p3[3] = {px, py, pd};
      #pragma unroll
      for (int c = 0; c < 3; ++c){
        float s, co;
        __sincosf(6.28318530717958647692f * p3[c], &s, &co);
        float* rb = row + 4 + c*12;
        #pragma unroll
        for (int f = 0; f < 6; ++f){
          rb[f] = s; rb[6+f] = co;
          float s2 = 2.f*s*co, c2 = 1.f - 2.f*s*s;
          s = s2; co = c2;
        }
      }
    } else {
      #pragma unroll
      for (int k = 0; k < 40; ++k) row[k] = 0.f;
    }
  }
  __syncthreads();
  int tr = t >> 3, tc = t & 7;
  float acc[4][8];
  #pragma unroll
  for (int i=0;i<4;++i)
    #pragma unroll
    for (int c=0;c<8;++c) acc[i][c] = 0.f;
  #pragma unroll 2
  for (int k4 = 0; k4 < 10; ++k4){
    float av4[4][4];
    #pragma unroll
    for (int i=0;i<4;++i){
      float4 aa = *(const float4*)&Alt[tr*4+i][k4*4];
      av4[i][0]=aa.x; av4[i][1]=aa.y; av4[i][2]=aa.z; av4[i][3]=aa.w;
    }
    #pragma unroll
    for (int j=0;j<4;++j){
      float4 lo = *(const float4*)&Wl[k4*4+j][tc*8];
      float4 hi = *(const float4*)&Wl[k4*4+j][tc*8+4];
      float wv[8];
      wv[0]=lo.x; wv[1]=lo.y; wv[2]=lo.z; wv[3]=lo.w;
      wv[4]=hi.x; wv[5]=hi.y; wv[6]=hi.z; wv[7]=hi.w;
      #pragma unroll
      for (int i=0;i<4;++i){
        float a = av4[i][j];
        #pragma unroll
        for (int c=0;c<8;++c) acc[i][c] += a*wv[c];
      }
    }
  }
  #pragma unroll
  for (int i=0;i<4;++i){
    int g = base + tr*4 + i;
    if (g >= TOTAL) continue;
    float ov[8];
    #pragma unroll
    for (int c=0;c<8;++c) ov[c] = acc[i][c] + B[tc*8+c];
    float* dst = &h[(size_t)g*64 + tc*8];
    *(float4*)dst       = *(const float4*)&ov[0];
    *(float4*)(dst + 4) = *(const float4*)&ov[4];
    if (hpre && g >= OFFS[4] && g < OFFS[9]){
      float* dp = hpre + (size_t)(g - OFFS[4])*64 + tc*8;
      *(float4*)dp       = *(const float4*)&ov[0];
      *(float4*)(dp + 4) = *(const float4*)&ov[4];
    }
  }
}

// ---------- emb tile: one wave embeds 16 nodes of level d at rowbase ----------
__device__ __forceinline__ void emb_tile(float* __restrict__ h,
    const unsigned short* __restrict__ EH, const unsigned short* __restrict__ ELo,
    const float* __restrict__ embB, const float* __restrict__ lng,
    const float* __restrict__ lnb, const float* __restrict__ gain,
    int d, size_t rowbase, int validN, int lane){
  int q = lane >> 4, li = lane & 15;
  const float* rp = h + (rowbase + li)*64 + q*8;
  float4 a0 = *(const float4*)rp;
  float4 a1 = *(const float4*)(rp + 4);
  float4 a2 = *(const float4*)(rp + 32);
  float4 a3 = *(const float4*)(rp + 36);
  short8 ah0, al0, ah1, al1;
  split8(a0, a1, ah0, al0);
  split8(a2, a3, ah1, al1);
  f32x4 acc0 = {0.f,0.f,0.f,0.f}, acc1 = acc0, acc2 = acc0, acc3 = acc0;
  #define EMB_CB(CB, ACC) { \
    size_t f0 = (((size_t)(d*2+0)*4 + (CB))*64 + lane)*8; \
    size_t f1 = (((size_t)(d*2+1)*4 + (CB))*64 + lane)*8; \
    short8 bh0 = *(const short8*)(EH + f0); \
    short8 bl0 = *(const short8*)(ELo + f0); \
    short8 bh1 = *(const short8*)(EH + f1); \
    short8 bl1 = *(const short8*)(ELo + f1); \
    ACC = __builtin_amdgcn_mfma_f32_16x16x32_bf16(ah0, bh0, ACC, 0,0,0); \
    ACC = __builtin_amdgcn_mfma_f32_16x16x32_bf16(al0, bh0, ACC, 0,0,0); \
    ACC = __builtin_amdgcn_mfma_f32_16x16x32_bf16(ah0, bl0, ACC, 0,0,0); \
    ACC = __builtin_amdgcn_mfma_f32_16x16x32_bf16(ah1, bh1, ACC, 0,0,0); \
    ACC = __builtin_amdgcn_mfma_f32_16x16x32_bf16(al1, bh1, ACC, 0,0,0); \
    ACC = __builtin_amdgcn_mfma_f32_16x16x32_bf16(ah1, bl1, ACC, 0,0,0); }
  EMB_CB(0, acc0)
  EMB_CB(1, acc1)
  EMB_CB(2, acc2)
  EMB_CB(3, acc3)
  #undef EMB_CB
  float b0 = embB[d*64 +      li];
  float b1 = embB[d*64 + 16 + li];
  float b2 = embB[d*64 + 32 + li];
  float b3 = embB[d*64 + 48 + li];
  float mu[4], rs[4];
  float z0[4], z1[4], z2[4], z3[4];
  #pragma unroll
  for (int r=0;r<4;++r){
    z0[r] = acc0[r] + b0;
    z1[r] = acc1[r] + b1;
    z2[r] = acc2[r] + b2;
    z3[r] = acc3[r] + b3;
    float s  = z0[r] + z1[r] + z2[r] + z3[r];
    float qv = z0[r]*z0[r] + z1[r]*z1[r] + z2[r]*z2[r] + z3[r]*z3[r];
    #pragma unroll
    for (int mk=1; mk<16; mk<<=1){
      s  += __shfl_xor(s, mk, 64);
      qv += __shfl_xor(qv, mk, 64);
    }
    float m = s * 0.015625f;
    mu[r] = m;
    rs[r] = rsqrtf(qv * 0.015625f - m*m + 1e-5f);
  }
  float g0 = lng[d*64 +      li], l0 = lnb[d*64 +      li];
  float g1 = lng[d*64 + 16 + li], l1 = lnb[d*64 + 16 + li];
  float g2 = lng[d*64 + 32 + li], l2 = lnb[d*64 + 32 + li];
  float g3 = lng[d*64 + 48 + li], l3 = lnb[d*64 + 48 + li];
  float gn = gain[d];
  #pragma unroll
  for (int r=0;r<4;++r){
    int ni = q*4 + r;
    if (ni < validN){
      float* row = h + (rowbase + ni)*64;
      row[     li] = ((z0[r] - mu[r])*rs[r]*g0 + l0)*gn;
      row[16 + li] = ((z1[r] - mu[r])*rs[r]*g1 + l1)*gn;
      row[32 + li] = ((z2[r] - mu[r])*rs[r]*g2 + l2)*gn;
      row[48 + li] = ((z3[r] - mu[r])*rs[r]*g3 + l3)*gn;
    }
  }
}

// ---------- conv (halo + fused pool + MFMA) + piggy-backed emb blocks ----------
// blocks < NC: conv for level (lbits); blocks >= NC: emb tiles of level embD.
__global__ __launch_bounds__(256) void k_conv_emb(float* __restrict__ h,
    const float* __restrict__ hPar,
    const unsigned short* __restrict__ WHl, const unsigned short* __restrict__ WLl,
    const float* __restrict__ Bb, int N, int offL, int offC, int lbits, int NC,
    const unsigned short* __restrict__ EH, const unsigned short* __restrict__ ELo,
    const float* __restrict__ embB, const float* __restrict__ lng,
    const float* __restrict__ lnb, const float* __restrict__ gain, int embD){
  __shared__ unsigned short haloH[100*72];
  __shared__ unsigned short haloL[100*72];
  __shared__ int hkey[100];
  int t = threadIdx.x;
  if ((int)blockIdx.x >= NC){
    int b2 = blockIdx.x - NC;
    int w = t >> 6, lane = t & 63;
    size_t base = (size_t)OFFS[embD] + ((size_t)b2*4 + w)*16;
    emb_tile(h, EH, ELo, embB, lng, lnb, gain, embD, base, 16, lane);
    return;
  }
  int nb = blockIdx.x * 64;
  int res = 1 << lbits;
  if (t < 100){
    int i = t % 10, j = t / 10;
    int gx = (int)deint((unsigned)nb) - 1 + i;
    int gy = (int)deint(((unsigned)nb)>>1) - 1 + j;
    bool ok = (gx>=0 && gy>=0 && gx<res && gy<res);
    hkey[t] = ok ? (int)(ileave((unsigned)gx) | (ileave((unsigned)gy)<<1)) : -1;
  }
  __syncthreads();
  const float* hC = h + (size_t)offC*64;
  for (int e = t; e < 1600; e += 256){
    int hi_ = e >> 4, u = e & 15;
    int key = hkey[hi_];
    float4 r = make_float4(0.f,0.f,0.f,0.f);
    if (key >= 0){
      const float4* c = (const float4*)(hC + (size_t)(4*key)*64) + u;
      float4 c0 = c[0], c1 = c[16], c2 = c[32], c3 = c[48];
      float4 pr = *((const float4*)(hPar + (size_t)key*64) + u);
      r.x = 0.25f*(c0.x+c1.x+c2.x+c3.x) + pr.x;
      r.y = 0.25f*(c0.y+c1.y+c2.y+c3.y) + pr.y;
      r.z = 0.25f*(c0.z+c1.z+c2.z+c3.z) + pr.z;
      r.w = 0.25f*(c0.w+c1.w+c2.w+c3.w) + pr.w;
    }
    unsigned short h0=f2bh(r.x), h1=f2bh(r.y), h2=f2bh(r.z), h3=f2bh(r.w);
    *(ushort4*)&haloH[hi_*72 + u*4] = make_ushort4(h0,h1,h2,h3);
    *(ushort4*)&haloL[hi_*72 + u*4] = make_ushort4(
        f2bh(r.x - bh2f(h0)), f2bh(r.y - bh2f(h1)),
        f2bh(r.z - bh2f(h2)), f2bh(r.w - bh2f(h3)));
  }
  __syncthreads();

  int cb   = __builtin_amdgcn_readfirstlane((int)(threadIdx.x >> 6));
  int lane = t & 63;
  int q = lane >> 4;
  int chl = cb*16 + (lane & 15);
  int lx0,ly0,lx1,ly1,lx2,ly2,lx3,ly3;
  {
    int n0 = (lane&15), n1 = 16+(lane&15), n2 = 32+(lane&15), n3 = 48+(lane&15);
    lx0=(int)deint((unsigned)n0); ly0=(int)deint(((unsigned)n0)>>1);
    lx1=(int)deint((unsigned)n1); ly1=(int)deint(((unsigned)n1)>>1);
    lx2=(int)deint((unsigned)n2); ly2=(int)deint(((unsigned)n2)>>1);
    lx3=(int)deint((unsigned)n3); ly3=(int)deint(((unsigned)n3)>>1);
  }
  f32x4 acc0 = {0.f,0.f,0.f,0.f}, acc1 = acc0, acc2 = acc0, acc3 = acc0;

  #pragma unroll 1
  for (int dy=0;dy<3;++dy){
    #pragma unroll 1
    for (int dx=0;dx<3;++dx){
      int m = dy*3 + dx;
      int r0 = (ly0+dy)*10 + lx0+dx;
      int r1 = (ly1+dy)*10 + lx1+dx;
      int r2 = (ly2+dy)*10 + lx2+dx;
      int r3 = (ly3+dy)*10 + lx3+dx;
      #pragma unroll
      for (int ks=0;ks<2;++ks){
        const unsigned short* fp = WHl + ((size_t)((m*2+ks)*4 + cb)*64 + lane)*8;
        const unsigned short* fq = WLl + ((size_t)((m*2+ks)*4 + cb)*64 + lane)*8;
        short8 bh = *(const short8*)fp;
        short8 bl = *(const short8*)fq;
        int so = (ks*4 + q)*8;
        short8 ah0 = *(const short8*)&haloH[r0*72 + so];
        short8 al0 = *(const short8*)&haloL[r0*72 + so];
        short8 ah1 = *(const short8*)&haloH[r1*72 + so];
        short8 al1 = *(const short8*)&haloL[r1*72 + so];
        short8 ah2 = *(const short8*)&haloH[r2*72 + so];
        short8 al2 = *(const short8*)&haloL[r2*72 + so];
        short8 ah3 = *(const short8*)&haloH[r3*72 + so];
        short8 al3 = *(const short8*)&haloL[r3*72 + so];
        acc0 = __builtin_amdgcn_mfma_f32_16x16x32_bf16(ah0, bh, acc0, 0,0,0);
        acc1 = __builtin_amdgcn_mfma_f32_16x16x32_bf16(ah1, bh, acc1, 0,0,0);
        acc2 = __builtin_amdgcn_mfma_f32_16x16x32_bf16(ah2, bh, acc2, 0,0,0);
        acc3 = __builtin_amdgcn_mfma_f32_16x16x32_bf16(ah3, bh, acc3, 0,0,0);
        acc0 = __builtin_amdgcn_mfma_f32_16x16x32_bf16(al0, bh, acc0, 0,0,0);
        acc1 = __builtin_amdgcn_mfma_f32_16x16x32_bf16(al1, bh, acc1, 0,0,0);
        acc2 = __builtin_amdgcn_mfma_f32_16x16x32_bf16(al2, bh, acc2, 0,0,0);
        acc3 = __builtin_amdgcn_mfma_f32_16x16x32_bf16(al3, bh, acc3, 0,0,0);
        acc0 = __builtin_amdgcn_mfma_f32_16x16x32_bf16(ah0, bl, acc0, 0,0,0);
        acc1 = __builtin_amdgcn_mfma_f32_16x16x32_bf16(ah1, bl, acc1, 0,0,0);
        acc2 = __builtin_amdgcn_mfma_f32_16x16x32_bf16(ah2, bl, acc2, 0,0,0);
        acc3 = __builtin_amdgcn_mfma_f32_16x16x32_bf16(ah3, bl, acc3, 0,0,0);
      }
    }
  }
  float bias = Bb[chl];
  int rowb = q*4;
  float* hO = h + (size_t)(offL + nb)*64;
  #pragma unroll
  for (int reg=0;reg<4;++reg){
    int n0 = rowb + reg;
    float v0 = acc0[reg] + bias; if (nb + n0      < N) hO[(size_t)(n0     )*64 + chl] = v0 > 0.f ? v0 : 0.f;
    float v1 = acc1[reg] + bias; if (nb + n0 + 16 < N) hO[(size_t)(n0 + 16)*64 + chl] = v1 > 0.f ? v1 : 0.f;
    float v2 = acc2[reg] + bias; if (nb + n0 + 32 < N) hO[(size_t)(n0 + 32)*64 + chl] = v2 > 0.f ? v2 : 0.f;
    float v3 = acc3[reg] + bias; if (nb + n0 + 48 < N) hO[(size_t)(n0 + 48)*64 + chl] = v3 > 0.f ? v3 : 0.f;
  }
}

// ---------- tail level (on-chip): m-loop reads Pt; pool next Pt from REGISTERS ----------
template<int L>
__device__ __forceinline__ void tail_level2(float* __restrict__ h,
    const unsigned short* __restrict__ WHc, const unsigned short* __restrict__ WLc,
    const float* __restrict__ convB, const float* __restrict__ Hpar,
    unsigned short* __restrict__ PtH, unsigned short* __restrict__ PtL, int t){
  constexpr int Np  = 1 << (2*L);
  constexpr int NTt = (Np + 15)/16;
  constexpr int TG  = (NTt + 3)/4;
  constexpr int res = 1 << L;
  int w  = t >> 6;
  int cb = __builtin_amdgcn_readfirstlane(w & 3);
  int tg = __builtin_amdgcn_readfirstlane(w >> 2);
  int lane = t & 63;
  int q = lane >> 4, li = lane & 15;
  int chl = cb*16 + li;
  int lx[TG], ly[TG];
  #pragma unroll
  for (int i=0;i<TG;++i){
    unsigned n = (unsigned)((tg*TG + i)*16 + li);
    lx[i] = (int)deint(n); ly[i] = (int)deint(n >> 1);
  }
  f32x4 acc[TG];
  #pragma unroll
  for (int i=0;i<TG;++i) acc[i] = f32x4{0.f,0.f,0.f,0.f};
  short8 bh0, bl0, bh1, bl1;
  {
    size_t f0 = ((size_t)(0*4 + cb)*64 + lane)*8;
    size_t f1 = ((size_t)(1*4 + cb)*64 + lane)*8;
    bh0 = *(const short8*)(WHc + f0); bl0 = *(const short8*)(WLc + f0);
    bh1 = *(const short8*)(WHc + f1); bl1 = *(const short8*)(WLc + f1);
  }
  #pragma unroll 1
  for (int m=0;m<9;++m){
    short8 nh0, nl0, nh1, nl1;
    if (m < 8){
      size_t f0 = ((size_t)(((m+1)*2+0)*4 + cb)*64 + lane)*8;
      size_t f1 = ((size_t)(((m+1)*2+1)*4 + cb)*64 + lane)*8;
      nh0 = *(const short8*)(WHc + f0); nl0 = *(const short8*)(WLc + f0);
      nh1 = *(const short8*)(WHc + f1); nl1 = *(const short8*)(WLc + f1);
    }
    int dy = m/3 - 1, dx = m%3 - 1;
    #pragma unroll
    for (int i=0;i<TG;++i){
      int nx = lx[i]+dx, ny = ly[i]+dy;
      int key = (nx>=0 && ny>=0 && nx<res && ny<res)
              ? (int)(ileave((unsigned)nx) | (ileave((unsigned)ny)<<1)) : Np;
      const unsigned short* pH = PtH + key*72;
      const unsigned short* pL = PtL + key*72;
      short8 ah0 = *(const short8*)(pH + q*8);
      short8 al0 = *(const short8*)(pL + q*8);
      short8 ah1 = *(const short8*)(pH + 32 + q*8);
      short8 al1 = *(const short8*)(pL + 32 + q*8);
      acc[i] = __builtin_amdgcn_mfma_f32_16x16x32_bf16(ah0, bh0, acc[i], 0,0,0);
      acc[i] = __builtin_amdgcn_mfma_f32_16x16x32_bf16(al0, bh0, acc[i], 0,0,0);
      acc[i] = __builtin_amdgcn_mfma_f32_16x16x32_bf16(ah0, bl0, acc[i], 0,0,0);
      acc[i] = __builtin_amdgcn_mfma_f32_16x16x32_bf16(ah1, bh1, acc[i], 0,0,0);
      acc[i] = __builtin_amdgcn_mfma_f32_16x16x32_bf16(al1, bh1, acc[i], 0,0,0);
      acc[i] = __builtin_amdgcn_mfma_f32_16x16x32_bf16(ah1, bl1, acc[i], 0,0,0);
    }
    if (m < 8){ bh0 = nh0; bl0 = nl0; bh1 = nh1; bl1 = nl1; }
  }
  float bias = convB[L*64 + chl];
  float vq[TG][4];
  #pragma unroll
  for (int i=0;i<TG;++i){
    #pragma unroll
    for (int reg=0;reg<4;++reg){
      int ni = (tg*TG + i)*16 + q*4 + reg;
      float v = acc[i][reg] + bias;
      v = v > 0.f ? v : 0.f;
      vq[i][reg] = v;
      if (ni < Np) h[(size_t)(OFFS[L] + ni)*64 + chl] = v;
    }
  }
  __syncthreads();
  if (L > 1){
    constexpr int Pp = Np/4;
    #pragma unroll
    for (int i=0;i<TG;++i){
      int p = (tg*TG + i)*4 + q;
      if (p < Pp){
        float pooled = 0.25f*(vq[i][0]+vq[i][1]+vq[i][2]+vq[i][3])
                     + Hpar[(size_t)(OFFS[L-1] + p)*64 + chl];
        unsigned short hh = f2bh(pooled);
        PtH[p*72 + chl] = hh;
        PtL[p*72 + chl] = f2bh(pooled - bh2f(hh));
      }
    }
    if (t < 64){ PtH[Pp*72 + t] = 0; PtL[Pp*72 + t] = 0; }
  } else {
    if (tg == 0 && q == 0){
      float pooled = 0.25f*(vq[0][0]+vq[0][1]+vq[0][2]+vq[0][3]) + Hpar[chl];
      h[chl] = pooled;
    }
  }
  __syncthreads();
}

// ---------- tail: block 0 = levels 3..1 + emb 0..4; blocks 1..4 = emb level 5 ----------
__global__ __launch_bounds__(1024) void k_tail(float* __restrict__ h,
    const unsigned short* __restrict__ WH, const unsigned short* __restrict__ WLo,
    const float* __restrict__ convB,
    const unsigned short* __restrict__ EH, const unsigned short* __restrict__ ELo,
    const float* __restrict__ embB, const float* __restrict__ lng,
    const float* __restrict__ lnb, const float* __restrict__ gain){
  __shared__ unsigned short PtH[65*72];
  __shared__ unsigned short PtL[65*72];
  __shared__ float Hpar[85*64];
  int t = threadIdx.x;
  int w = t >> 6, lane = t & 63;
  if (blockIdx.x != 0){
    // emb level 5: 64 tiles over blocks 1..4 x 16 waves
    size_t base = (size_t)OFFS[5] + ((size_t)(blockIdx.x - 1)*16 + w)*16;
    emb_tile(h, EH, ELo, embB, lng, lnb, gain, 5, base, 16, lane);
    return;
  }
  for (int e = t; e < 85*16; e += 1024)
    ((float4*)Hpar)[e] = ((const float4*)h)[e];
  // stage Pt for L=3: pooled = 0.25*sum(children h[4]) + parent h[3]; row 64 = zero
  for (int e = t; e < 65*16; e += 1024){
    int node = e >> 4, u = e & 15;
    float4 r = make_float4(0.f,0.f,0.f,0.f);
    if (node < 64){
      const float4* c = (const float4*)(h + (size_t)(OFFS[4] + 4*node)*64) + u;
      float4 c0 = c[0], c1 = c[16], c2 = c[32], c3 = c[48];
      float4 pr = *((const float4*)(h + (size_t)(OFFS[3] + node)*64) + u);
      r.x = 0.25f*(c0.x+c1.x+c2.x+c3.x) + pr.x;
      r.y = 0.25f*(c0.y+c1.y+c2.y+c3.y) + pr.y;
      r.z = 0.25f*(c0.z+c1.z+c2.z+c3.z) + pr.z;
      r.w = 0.25f*(c0.w+c1.w+c2.w+c3.w) + pr.w;
    }
    unsigned short h0=f2bh(r.x), h1=f2bh(r.y), h2=f2bh(r.z), h3=f2bh(r.w);
    *(ushort4*)&PtH[node*72 + u*4] = make_ushort4(h0,h1,h2,h3);
    *(ushort4*)&PtL[node*72 + u*4] = make_ushort4(
        f2bh(r.x - bh2f(h0)), f2bh(r.y - bh2f(h1)),
        f2bh(r.z - bh2f(h2)), f2bh(r.w - bh2f(h3)));
  }
  __syncthreads();
  tail_level2<3>(h, WH + (size_t)2*36864, WLo + (size_t)2*36864, convB, Hpar, PtH, PtL, t);
  tail_level2<2>(h, WH + (size_t)1*36864, WLo + (size_t)1*36864, convB, Hpar, PtH, PtL, t);
  tail_level2<1>(h, WH,                   WLo,                   convB, Hpar, PtH, PtL, t);
  // epilogue: emb levels 0..4 (23 tile-jobs over 16 waves)
  for (int j = w; j < 23; j += 16){
    int d, tile;
    if (j < 16)      { d=4; tile=j;    }
    else if (j < 20) { d=3; tile=j-16; }
    else if (j == 20){ d=2; tile=0;    }
    else if (j == 21){ d=1; tile=0;    }
    else             { d=0; tile=0;    }
    int Nlev = 1 << (2*d);
    int valid = Nlev - tile*16;
    emb_tile(h, EH, ELo, embB, lng, lnb, gain, d,
             (size_t)OFFS[d] + (size_t)tile*16, valid > 16 ? 16 : valid, lane);
  }
}

extern "C" void kernel_launch(void* const* d_in, const int* in_sizes, int n_in,
                              void* d_out, int out_size, void* d_ws, size_t ws_size,
                              hipStream_t stream) {
  (void)in_sizes; (void)n_in; (void)out_size;
  const float* feat  = (const float*)d_in[0];
  const float* ipW   = (const float*)d_in[1];
  const float* ipB   = (const float*)d_in[2];
  const float* convW = (const float*)d_in[3];
  const float* convB = (const float*)d_in[4];
  const float* embW  = (const float*)d_in[5];
  const float* embB  = (const float*)d_in[6];
  const float* lng   = (const float*)d_in[7];
  const float* lnb   = (const float*)d_in[8];
  const float* gain  = (const float*)d_in[9];
  float* h = (float*)d_out;

  unsigned short* WH  = (unsigned short*)d_ws;
  unsigned short* WLo = WH + FRAG_USH;
  const unsigned short* EH  = WH  + CONV_USH;
  const unsigned short* ELo = WLo + CONV_USH;
  float* hpre = (ws_size >= FRAG_BYTES + HPRE_BYTES)
              ? (float*)((char*)d_ws + FRAG_BYTES) : nullptr;

  k_wprep<<<164, 256, 0, stream>>>(convW, embW, WH, WLo);
  k_inproj<<<(TOTAL + 127)/128, 256, 0, stream>>>(feat, ipW, ipB, h, hpre);

  // conv L=8..4; emb(L+2) piggy-backs once its level is final (read by conv L+1)
  // embD per conv launch: L=8 -> none; 7->9; 6->8; 5->7; 4->6
  for (int L = 8; L >= 4; --L){
    int Np = 1 << (2*L);
    int NC = Np/64;
    int embD = (L <= 7) ? L + 2 : -1;
    int embBlocks = (embD > 0) ? (1 << (2*embD)) / 64 : 0;  // 64 nodes per block
    const float* hPar = hpre ? (hpre + (size_t)(OFFS[L] - OFFS[4])*64)
                             : (h + (size_t)OFFS[L]*64);
    k_conv_emb<<<NC + embBlocks, 256, 0, stream>>>(h, hPar,
        WH  + (size_t)(L-1)*36864, WLo + (size_t)(L-1)*36864,
        convB + (size_t)L*64, Np, OFFS[L], OFFS[L+1], L, NC,
        EH, ELo, embB, lng, lnb, gain, embD);
  }

  // tail: 1 block levels 3..1 + emb 0..4; blocks 1..4 emb level 5
  k_tail<<<5, 1024, 0, stream>>>(h, WH, WLo, convB,
      EH, ELo, embB, lng, lnb, gain);
}